// Round 5
// baseline (188.724 us; speedup 1.0000x reference)
//
#include <hip/hip_runtime.h>

// GruBlock round 4b: one wave per (sequence, direction); zero barriers.
// 6144 blocks x 64 threads. Each wave: prefetch x chunk (regs) -> xt LDS (f16)
// -> MFMA projection (pre = W2 @ x, W2 = wih@conv_w folded, f16) -> s_pre LDS
// -> 16-step GRU scan with k-split halves (lane = kh*32+j computes 16-k partial
// sums, combined via __shfl_xor 32), h broadcast via 128B s_h.
// xt rows padded to 18 f16 (de-aliases 8-row groups onto bank sets 0/8/16/24).
// (R4 fix: cvt_pkrtz returns __fp16x2, not _Float16x2 — use pk16 alias.)

typedef _Float16 f16x8 __attribute__((ext_vector_type(8)));
typedef __fp16   pk16  __attribute__((ext_vector_type(2)));
typedef float f32x4 __attribute__((ext_vector_type(4)));

#define HWSTRIDE 7680   // 48*160
#define NCHUNK 10
#define WS_BIAS_OFF 24576

__global__ void fold_weights(const float* __restrict__ conv_w,
                             const float* __restrict__ conv_b,
                             const float* __restrict__ wih_f,
                             const float* __restrict__ bih_f,
                             const float* __restrict__ bhh_f,
                             const float* __restrict__ wih_b,
                             const float* __restrict__ bih_b,
                             const float* __restrict__ bhh_b,
                             void* wsv)
{
    _Float16* W2 = (_Float16*)wsv;
    float* bias = (float*)((char*)wsv + WS_BIAS_OFF);
    const int idx = blockIdx.x * 256 + threadIdx.x;
    if (idx < 12288) {
        const int d = idx / 6144, r = idx % 6144, g = r / 64, c = r % 64;
        const float* wih = d ? wih_b : wih_f;
        float acc = 0.f;
        for (int o = 0; o < 64; ++o) acc += wih[g * 64 + o] * conv_w[o * 64 + c];
        W2[idx] = (_Float16)acc;
    } else if (idx < 12288 + 256) {
        const int e = idx - 12288;
        const int d = e >> 7, rr = e & 127, kind = rr >> 5, j = rr & 31;
        const float* wih = d ? wih_b : wih_f;
        const float* bih = d ? bih_b : bih_f;
        const float* bhh = d ? bhh_b : bhh_f;
        float v;
        if (kind == 0 || kind == 1) {
            const int g = j + kind * 32;
            float b2 = bih[g];
            for (int o = 0; o < 64; ++o) b2 += wih[g * 64 + o] * conv_b[o];
            v = b2 + bhh[g];
        } else if (kind == 2) {
            const int g = j + 64;
            float b2 = bih[g];
            for (int o = 0; o < 64; ++o) b2 += wih[g * 64 + o] * conv_b[o];
            v = b2;
        } else {
            v = bhh[j + 64];
        }
        bias[(d * 4 + kind) * 32 + j] = v;
    }
}

__global__ __launch_bounds__(64, 3)
void gru_fused4(const float* __restrict__ x,
                const float* __restrict__ whh_f,
                const float* __restrict__ whh_b,
                const void* __restrict__ wsv,
                float* __restrict__ out)
{
    __shared__ __align__(16) _Float16 xt[64][18];    // 2.25 KB, pad 18
    __shared__ __align__(16) _Float16 s_pre[16][104];// 3.25 KB
    __shared__ __align__(16) float s_h[32];

    const int d    = blockIdx.x & 1;
    const int n    = blockIdx.x >> 1;
    const int b    = n / 48;
    const int h    = n % 48;
    const int lane = threadIdx.x;
    const int kh   = lane >> 5;        // k-half
    const int j    = lane & 31;        // hidden index
    const int t16  = lane & 15;        // mfma col / A row
    const int g8   = (lane >> 4) * 8;  // mfma k-slice base
    const int sc   = lane >> 2;        // staging channel base
    const int stq  = lane & 3;         // staging t-quad

    const float* xbase = x + (size_t)b * (64 * HWSTRIDE) + (size_t)h * 160;

    // ---- persistent weights ----
    const _Float16* W2 = (const _Float16*)wsv + (size_t)d * 96 * 64;
    f16x8 A[6][2];
    #pragma unroll
    for (int gt = 0; gt < 6; ++gt)
        #pragma unroll
        for (int kt = 0; kt < 2; ++kt)
            A[gt][kt] = *(const f16x8*)&W2[(gt * 16 + t16) * 64 + kt * 32 + g8];

    const float* whh = d ? whh_b : whh_f;
    float w[48];   // [gate][k'] k' = 16*kh + 0..15
    #pragma unroll
    for (int g = 0; g < 3; ++g)
        #pragma unroll
        for (int q = 0; q < 4; ++q) {
            const float4 wv = *(const float4*)&whh[(j + 32 * g) * 32 + kh * 16 + q * 4];
            w[g * 16 + q * 4 + 0] = wv.x; w[g * 16 + q * 4 + 1] = wv.y;
            w[g * 16 + q * 4 + 2] = wv.z; w[g * 16 + q * 4 + 3] = wv.w;
        }
    const float* bias = (const float*)((const char*)wsv + WS_BIAS_OFF);
    const float bc_r = bias[(d * 4 + 0) * 32 + j];
    const float bc_z = bias[(d * 4 + 1) * 32 + j];
    const float b2n  = bias[(d * 4 + 2) * 32 + j];
    const float bhn  = bias[(d * 4 + 3) * 32 + j];

    float* orow = out + (((size_t)b * 64 + (size_t)(d * 32 + j)) * 48 + h) * 160;

    // ---- helpers ----
    float4 pf[4];
    auto issue_pf = [&](int cc) {
        const int w0 = d ? (144 - cc * 16) : (cc * 16);
        #pragma unroll
        for (int k = 0; k < 4; ++k)
            pf[k] = *(const float4*)(xbase + (size_t)(sc + 16 * k) * HWSTRIDE + w0 + stq * 4);
    };
    auto write_xt = [&]() {
        #pragma unroll
        for (int k = 0; k < 4; ++k) {
            pk16 lo = __builtin_amdgcn_cvt_pkrtz(pf[k].x, pf[k].y);
            pk16 hi = __builtin_amdgcn_cvt_pkrtz(pf[k].z, pf[k].w);
            *(pk16*)&xt[sc + 16 * k][stq * 4]     = lo;
            *(pk16*)&xt[sc + 16 * k][stq * 4 + 2] = hi;
        }
    };
    auto project = [&]() {
        f16x8 bf0, bf1;
        #pragma unroll
        for (int e = 0; e < 8; ++e) {
            bf0[e] = xt[g8 + e][t16];
            bf1[e] = xt[32 + g8 + e][t16];
        }
        const int row = d ? (15 - t16) : t16;
        #pragma unroll
        for (int gt = 0; gt < 6; ++gt) {
            f32x4 acc = {0.f, 0.f, 0.f, 0.f};
            acc = __builtin_amdgcn_mfma_f32_16x16x32_f16(A[gt][0], bf0, acc, 0, 0, 0);
            acc = __builtin_amdgcn_mfma_f32_16x16x32_f16(A[gt][1], bf1, acc, 0, 0, 0);
            pk16 o0 = __builtin_amdgcn_cvt_pkrtz(acc[0], acc[1]);
            pk16 o1 = __builtin_amdgcn_cvt_pkrtz(acc[2], acc[3]);
            *(pk16*)&s_pre[row][gt * 16 + (lane >> 4) * 4]     = o0;
            *(pk16*)&s_pre[row][gt * 16 + (lane >> 4) * 4 + 2] = o1;
        }
    };

    // ---- prologue ----
    issue_pf(0);
    write_xt();
    issue_pf(1);
    project();
    if (kh == 0) s_h[j] = 0.f;
    float hcur = 0.f;

    // ---- main loop ----
    for (int ci = 0; ci < NCHUNK; ++ci) {
        float hh[8];
        #pragma unroll
        for (int s = 0; s < 16; ++s) {
            const float pr = (float)s_pre[s][j];
            const float pz = (float)s_pre[s][j + 32];
            const float pn = (float)s_pre[s][j + 64];
            float4 h4[4];
            #pragma unroll
            for (int q = 0; q < 4; ++q) h4[q] = ((const float4*)&s_h[16 * kh])[q];
            const float* hv = (const float*)h4;
            float ar0 = 0.f, az0 = 0.f, an0 = 0.f;
            float ar1 = 0.f, az1 = 0.f, an1 = 0.f;
            #pragma unroll
            for (int k = 0; k < 16; k += 2) {
                const float h0 = hv[k], h1 = hv[k + 1];
                ar0 = fmaf(w[k],          h0, ar0);
                az0 = fmaf(w[16 + k],     h0, az0);
                an0 = fmaf(w[32 + k],     h0, an0);
                ar1 = fmaf(w[k + 1],      h1, ar1);
                az1 = fmaf(w[17 + k],     h1, az1);
                an1 = fmaf(w[33 + k],     h1, an1);
            }
            float ar = ar0 + ar1, az = az0 + az1, an = an0 + an1;
            ar += __shfl_xor(ar, 32);
            az += __shfl_xor(az, 32);
            an += __shfl_xor(an, 32);
            const float gr = ar + pr + bc_r;
            const float gz = az + pz + bc_z;
            const float r = __builtin_amdgcn_rcpf(1.f + __expf(-gr));
            const float z = __builtin_amdgcn_rcpf(1.f + __expf(-gz));
            float ta = (pn + b2n) + r * (an + bhn);
            ta = fminf(fmaxf(ta, -15.f), 15.f);
            const float e2 = __expf(2.f * ta);
            const float nn = (e2 - 1.f) * __builtin_amdgcn_rcpf(e2 + 1.f);
            hcur = (1.f - z) * nn + z * hcur;
            if (kh == 0) s_h[j] = hcur;
            asm volatile("" ::: "memory");
            if ((s >> 3) == kh) hh[s & 7] = hcur;
        }
        // ---- store this chunk's outputs (each lane: 2 float4) ----
        if (d == 0) {
            *(float4*)&orow[ci * 16 + 8 * kh] =
                make_float4(hh[0], hh[1], hh[2], hh[3]);
            *(float4*)&orow[ci * 16 + 8 * kh + 4] =
                make_float4(hh[4], hh[5], hh[6], hh[7]);
        } else {
            *(float4*)&orow[156 - ci * 16 - 8 * kh] =
                make_float4(hh[3], hh[2], hh[1], hh[0]);
            *(float4*)&orow[152 - ci * 16 - 8 * kh] =
                make_float4(hh[7], hh[6], hh[5], hh[4]);
        }
        // ---- prepare next chunk ----
        if (ci < NCHUNK - 1) {
            write_xt();                       // chunk ci+1 (prefetched)
            if (ci < NCHUNK - 2) issue_pf(ci + 2);
            project();                        // chunk ci+1 -> s_pre
        }
    }
}

extern "C" void kernel_launch(void* const* d_in, const int* in_sizes, int n_in,
                              void* d_out, int out_size, void* d_ws, size_t ws_size,
                              hipStream_t stream) {
    (void)in_sizes; (void)n_in; (void)ws_size; (void)out_size;
    fold_weights<<<dim3(49), dim3(256), 0, stream>>>(
        (const float*)d_in[1],  // conv_w
        (const float*)d_in[2],  // conv_b
        (const float*)d_in[3],  // wih_f
        (const float*)d_in[5],  // bih_f
        (const float*)d_in[6],  // bhh_f
        (const float*)d_in[7],  // wih_b
        (const float*)d_in[9],  // bih_b
        (const float*)d_in[10], // bhh_b
        d_ws);
    gru_fused4<<<dim3(6144), dim3(64), 0, stream>>>(
        (const float*)d_in[0],  // x
        (const float*)d_in[4],  // whh_f
        (const float*)d_in[8],  // whh_b
        d_ws,
        (float*)d_out);
}